// Round 3
// baseline (109.079 us; speedup 1.0000x reference)
//
#include <hip/hip_runtime.h>
#include <math.h>

#define BB 32
#define TT 4096
#define HH 512
#define QQS 512
#define TS 64            // chunks per batch
#define CH 64            // rows per chunk (TS*CH == TT)

#define TANH_K 2.8853900817779268f   // 2*log2(e)

__device__ inline float fast_exp2(float x) {
#if __has_builtin(__builtin_amdgcn_exp2f)
    return __builtin_amdgcn_exp2f(x);
#else
    return __expf(x * 0.6931471805599453f);
#endif
}
__device__ inline float fast_rcp(float x) {
#if __has_builtin(__builtin_amdgcn_rcpf)
    return __builtin_amdgcn_rcpf(x);
#else
    return 1.f / x;
#endif
}

__device__ inline float wave_reduce_sum(float v) {
#pragma unroll
    for (int off = 32; off > 0; off >>= 1) v += __shfl_xor(v, off, 64);
    return v;
}

__device__ inline float wave_reduce_max(float v) {
#pragma unroll
    for (int off = 32; off > 0; off >>= 1) v = fmaxf(v, __shfl_xor(v, off, 64));
    return v;
}

// q[b][h] = sum_s query[b][s] * Wq[h][s]; one wave per (b,h)
__global__ void qproj_kernel(const float* __restrict__ query,
                             const float* __restrict__ Wq,
                             float* __restrict__ qout) {
    int wid  = (blockIdx.x * blockDim.x + threadIdx.x) >> 6;
    int lane = threadIdx.x & 63;
    int b = wid >> 9;        // / HH
    int h = wid & (HH - 1);
    const float4* qr = (const float4*)(query + (size_t)b * QQS);
    const float4* wr = (const float4*)(Wq + (size_t)h * QQS);
    float4 a0 = qr[lane],      w0 = wr[lane];
    float4 a1 = qr[lane + 64], w1 = wr[lane + 64];
    float acc = a0.x * w0.x + a0.y * w0.y + a0.z * w0.z + a0.w * w0.w
              + a1.x * w1.x + a1.y * w1.y + a1.z * w1.z + a1.w * w1.w;
    acc = wave_reduce_sum(acc);
    if (lane == 0) qout[wid] = acc;
}

// tanh contribution: th = 1 - 2*rcp(exp2(k*K + qc) + 1); p += th * w
__device__ inline float tanh_term(float k, float qc, float w, float p) {
    float e = fast_exp2(fmaf(k, TANH_K, qc));
    float r = fast_rcp(e + 1.f);
    float th = fmaf(-2.f, r, 1.f);
    return fmaf(th, w, p);
}

// Fused: per (b, chunk) block -> scores, chunk softmax stats, partial context.
// Writes UNNORMALIZED exp(s - m_c) into alphas; finalize rescales in place.
__global__ __launch_bounds__(256) void fused_kernel(
        const float* __restrict__ key, const float* __restrict__ value,
        const float* __restrict__ qb,  const float* __restrict__ We,
        float* __restrict__ alphas, float* __restrict__ mbuf,
        float* __restrict__ zbuf,   float* __restrict__ part) {
    __shared__ float s_lds[CH];
    __shared__ float e_lds[CH];
    __shared__ float ctx_lds[HH];

    int b = blockIdx.x / TS, c = blockIdx.x % TS;
    int tid = threadIdx.x;
    int w = tid >> 6, lane = tid & 63;
    size_t row0 = (size_t)b * TT + (size_t)c * CH;

    // q*K and We held in registers for the whole phase (lane-invariant per row)
    const float4* qv = (const float4*)(qb + (size_t)b * HH);
    const float4* wv = (const float4*)We;
    float4 q0 = qv[lane], q1 = qv[lane + 64];
    float4 w0 = wv[lane], w1 = wv[lane + 64];
    q0.x *= TANH_K; q0.y *= TANH_K; q0.z *= TANH_K; q0.w *= TANH_K;
    q1.x *= TANH_K; q1.y *= TANH_K; q1.z *= TANH_K; q1.w *= TANH_K;

    // Phase A: scores for CH rows; wave w does rows {rr*8+w, rr*8+w+4}
#pragma unroll 2
    for (int rr = 0; rr < CH / 8; ++rr) {
        int r0 = rr * 8 + w, r1 = r0 + 4;
        const float4* k0p = (const float4*)(key + (row0 + r0) * HH);
        const float4* k1p = (const float4*)(key + (row0 + r1) * HH);
        float4 ka = k0p[lane], kb = k0p[lane + 64];
        float4 kc = k1p[lane], kd = k1p[lane + 64];
        float p0 = 0.f, p1 = 0.f;
        p0 = tanh_term(ka.x, q0.x, w0.x, p0);
        p0 = tanh_term(ka.y, q0.y, w0.y, p0);
        p0 = tanh_term(ka.z, q0.z, w0.z, p0);
        p0 = tanh_term(ka.w, q0.w, w0.w, p0);
        p0 = tanh_term(kb.x, q1.x, w1.x, p0);
        p0 = tanh_term(kb.y, q1.y, w1.y, p0);
        p0 = tanh_term(kb.z, q1.z, w1.z, p0);
        p0 = tanh_term(kb.w, q1.w, w1.w, p0);
        p1 = tanh_term(kc.x, q0.x, w0.x, p1);
        p1 = tanh_term(kc.y, q0.y, w0.y, p1);
        p1 = tanh_term(kc.z, q0.z, w0.z, p1);
        p1 = tanh_term(kc.w, q0.w, w0.w, p1);
        p1 = tanh_term(kd.x, q1.x, w1.x, p1);
        p1 = tanh_term(kd.y, q1.y, w1.y, p1);
        p1 = tanh_term(kd.z, q1.z, w1.z, p1);
        p1 = tanh_term(kd.w, q1.w, w1.w, p1);
        // paired reduce: lanes<32 end with sum(p0), lanes>=32 with sum(p1)
        float a0 = __shfl_xor(p0, 32, 64);
        float a1 = __shfl_xor(p1, 32, 64);
        float ws = (lane < 32) ? (p0 + a0) : (p1 + a1);
#pragma unroll
        for (int off = 16; off > 0; off >>= 1) ws += __shfl_xor(ws, off, 64);
        if ((lane & 31) == 0) s_lds[(lane < 32) ? r0 : r1] = ws;
    }
    __syncthreads();

    // Phase B: wave 0 -> chunk max, exp, sum; raw e -> alphas
    if (w == 0) {
        float s = s_lds[lane];
        float m = wave_reduce_max(s);
        float e = __expf(s - m);
        e_lds[lane] = e;
        alphas[row0 + lane] = e;
        float z = wave_reduce_sum(e);
        if (lane == 0) {
            mbuf[b * TS + c] = m;
            zbuf[b * TS + c] = z;
        }
    }
    __syncthreads();

    // Phase C: exp-weighted partial context over the chunk's value rows
    int d4 = tid & 127, rg = tid >> 7;
    const float4* vp = (const float4*)(value + row0 * HH);
    float4 acc = make_float4(0.f, 0.f, 0.f, 0.f);
#pragma unroll 4
    for (int r = rg * 32; r < rg * 32 + 32; ++r) {
        float a = e_lds[r];
        float4 v = vp[(size_t)r * (HH / 4) + d4];
        acc.x += a * v.x; acc.y += a * v.y; acc.z += a * v.z; acc.w += a * v.w;
    }
    if (rg == 0) ((float4*)ctx_lds)[d4] = acc;
    __syncthreads();
    if (rg == 1) {
        float4 t = ((float4*)ctx_lds)[d4];
        t.x += acc.x; t.y += acc.y; t.z += acc.z; t.w += acc.w;
        ((float4*)(part + ((size_t)c * BB + b) * HH))[d4] = t;
    }
}

// Finalize: blocks 0..31 -> rescale alphas in place; blocks 32..95 -> context
__global__ void finalize_kernel(const float* __restrict__ mbuf,
                                const float* __restrict__ zbuf,
                                const float* __restrict__ part,
                                float* __restrict__ alphas,
                                float* __restrict__ ctx) {
    int tid = threadIdx.x, lane = tid & 63;
    __shared__ float scale[TS];
    if (blockIdx.x < BB) {
        int b = blockIdx.x;
        // all 4 waves redundantly compute M, Z (lane spans TS=64)
        float m_l = mbuf[b * TS + lane];
        float z_l = zbuf[b * TS + lane];
        float M = wave_reduce_max(m_l);
        float Z = wave_reduce_sum(__expf(m_l - M) * z_l);
        float invZ = 1.f / Z;
        if (tid < TS) scale[tid] = __expf(m_l - M) * invZ;
        __syncthreads();
        float4* ap = (float4*)(alphas + (size_t)b * TT);
#pragma unroll
        for (int i = 0; i < 4; ++i) {
            int idx = tid + i * 256;
            float4 a = ap[idx];
            float s = scale[idx >> 4];      // 16 float4 = 64 floats per chunk
            a.x *= s; a.y *= s; a.z *= s; a.w *= s;
            ap[idx] = a;
        }
    } else {
        int i = blockIdx.x - BB;     // 0..63
        int b = i >> 1;
        int d = (i & 1) * 256 + tid;
        float m_l = mbuf[b * TS + lane];
        float z_l = zbuf[b * TS + lane];
        float M = wave_reduce_max(m_l);
        float Z = wave_reduce_sum(__expf(m_l - M) * z_l);
        if (tid < TS) scale[tid] = __expf(m_l - M) / Z;
        __syncthreads();
        float s = 0.f;
#pragma unroll
        for (int c2 = 0; c2 < TS; ++c2)
            s += scale[c2] * part[((size_t)c2 * BB + b) * HH + d];
        ctx[(size_t)b * HH + d] = s;
    }
}

extern "C" void kernel_launch(void* const* d_in, const int* in_sizes, int n_in,
                              void* d_out, int out_size, void* d_ws, size_t ws_size,
                              hipStream_t stream) {
    const float* query = (const float*)d_in[0];
    const float* key   = (const float*)d_in[1];
    const float* value = (const float*)d_in[2];
    // d_in[3] = mask (unused by reference forward)
    const float* Wq    = (const float*)d_in[4];
    const float* We    = (const float*)d_in[5];

    float* ctx    = (float*)d_out;            // [B,1,H]
    float* alphas = (float*)d_out + BB * HH;  // [B,T]

    float* qbuf   = (float*)d_ws;                    // B*H
    float* mbuf   = qbuf + BB * HH;                  // B*TS
    float* zbuf   = mbuf + BB * TS;                  // B*TS
    float* part   = zbuf + BB * TS;                  // TS*B*H

    qproj_kernel<<<(BB * HH) / 4, 256, 0, stream>>>(query, Wq, qbuf);
    fused_kernel<<<BB * TS, 256, 0, stream>>>(key, value, qbuf, We, alphas, mbuf, zbuf, part);
    finalize_kernel<<<BB + 2 * BB, 256, 0, stream>>>(mbuf, zbuf, part, alphas, ctx);
}